// Round 1
// baseline (66.944 us; speedup 1.0000x reference)
//
#include <hip/hip_runtime.h>
#include <hip/hip_bf16.h>
#include <cstdint>

// SKANLinear: out[b][o] = sum_i relu(w[o][i] * x_aug[b][i]),  x_aug = [x, 1]
// Identity: relu(p) = (p+|p|)/2 and |w*x|=|w|*|x|  =>
//   out = (x @ (w/2)^T) + (|x| @ (|w|/2)^T) + relu(w[:,256])
// Implemented as ONE bf16 GEMM with K=512: interleave (x,|x|) and (w/2,|w|/2).

typedef short short8 __attribute__((ext_vector_type(8)));   // 8 x bf16 bits
typedef float f32x4 __attribute__((ext_vector_type(4)));

#define IN_F 256
#define OUT_F 256
#define KC 512
#define BM 32
#define BN 64
#define BK 64
#define NSTEP (KC / BK)   // 8

static __device__ __forceinline__ short f2bf(float f) {
    return __builtin_bit_cast(short, static_cast<__bf16>(f));
}

// ---- Kernel 1: weight prep ----
// w: [256][257] f32.  Wcat: [256][512] bf16 bits, Wcat[o][2j+s] = bf16( s ? |w|/2 : w/2 ).
// bias[o] = relu(w[o][256]).
__global__ __launch_bounds__(64) void prep_kernel(const float* __restrict__ w,
                                                  short* __restrict__ Wcat,
                                                  float* __restrict__ bias) {
    const int o = blockIdx.x;
    const int t = threadIdx.x;
    const float* wr = w + (size_t)o * 257;
    float v[4];
#pragma unroll
    for (int j = 0; j < 4; ++j) v[j] = wr[t * 4 + j];   // cols 4t..4t+3 (0..255)
    short8 c;
#pragma unroll
    for (int j = 0; j < 4; ++j) {
        float h = 0.5f * v[j];
        c[2 * j]     = f2bf(h);
        c[2 * j + 1] = f2bf(__builtin_fabsf(h));
    }
    *reinterpret_cast<short8*>(Wcat + (size_t)o * KC + t * 8) = c;
    if (t == 0) bias[o] = __builtin_fmaxf(wr[256], 0.0f);
}

// ---- Kernel 2: fused x-convert + bf16 GEMM ----
// grid (8192/BM, 256/BN) = (256,4), 256 threads (4 waves, 2x2 wave grid).
__global__ __launch_bounds__(256, 4) void skan_gemm(const float* __restrict__ x,
                                                    const short* __restrict__ Wcat,
                                                    const float* __restrict__ bias,
                                                    float* __restrict__ out) {
    __shared__ short Asm[2][BM][BK];   // 2 x 4 KB  (x,|x| interleaved, halved-K view)
    __shared__ short Bsm[2][BN][BK];   // 2 x 8 KB

    const int tid  = threadIdx.x;
    const int lane = tid & 63;
    const int wid  = tid >> 6;
    const int wr   = wid >> 1;      // wave row (0..1) -> 16 rows each
    const int wc   = wid & 1;       // wave col (0..1) -> 32 cols each
    const int m0   = blockIdx.x * BM;
    const int n0   = blockIdx.y * BN;

    // A staging: thread t handles row ar=t>>3, 4 f32 at col 4*(t&7) of the k-step slice
    const int ar = tid >> 3, ac = tid & 7;
    const float* aptr = x + (size_t)(m0 + ar) * IN_F + ac * 4;
    char* abase = (char*)&Asm[0][0][0];
    const int a_off = ar * 128 + ((ac ^ (ar & 7)) << 4);    // swizzled 16B chunk

    // B staging: thread t handles row br=t>>2, 32B (2 chunks) at seg=t&3
    const int br = tid >> 2, bseg = tid & 3;
    const short* bptr = Wcat + (size_t)(n0 + br) * KC + bseg * 16;
    char* bbase = (char*)&Bsm[0][0][0];
    const int b_off0 = br * 128 + (((bseg * 2)     ^ (br & 7)) << 4);
    const int b_off1 = br * 128 + (((bseg * 2 + 1) ^ (br & 7)) << 4);

    f32x4 acc[2] = {};
    float4 areg;
    short8 breg0, breg1;

    auto loadRegs = [&](int kk) {
        areg  = *reinterpret_cast<const float4*>(aptr + kk * 32);       // 32 f32 cols/step
        breg0 = *reinterpret_cast<const short8*>(bptr + kk * BK);
        breg1 = *reinterpret_cast<const short8*>(bptr + kk * BK + 8);
    };
    auto writeLds = [&](int buf) {
        short8 av;
        const float vv[4] = {areg.x, areg.y, areg.z, areg.w};
#pragma unroll
        for (int j = 0; j < 4; ++j) {
            av[2 * j]     = f2bf(vv[j]);
            av[2 * j + 1] = f2bf(__builtin_fabsf(vv[j]));
        }
        *reinterpret_cast<short8*>(abase + buf * (BM * BK * 2) + a_off)  = av;
        *reinterpret_cast<short8*>(bbase + buf * (BN * BK * 2) + b_off0) = breg0;
        *reinterpret_cast<short8*>(bbase + buf * (BN * BK * 2) + b_off1) = breg1;
    };
    auto compute = [&](int buf) {
        const char* ab = abase + buf * (BM * BK * 2);
        const char* bb = bbase + buf * (BN * BK * 2);
        const int arow  = wr * 16 + (lane & 15);
        const int bcol0 = wc * 32 + (lane & 15);
        const int kg    = lane >> 4;
#pragma unroll
        for (int ks = 0; ks < 2; ++ks) {
            const int chunk = ks * 4 + kg;
            short8 af = *reinterpret_cast<const short8*>(
                ab + arow * 128 + ((chunk ^ (arow & 7)) << 4));
#pragma unroll
            for (int f = 0; f < 2; ++f) {
                const int bcol = bcol0 + f * 16;
                short8 bfr = *reinterpret_cast<const short8*>(
                    bb + bcol * 128 + ((chunk ^ (bcol & 7)) << 4));
                acc[f] = __builtin_amdgcn_mfma_f32_16x16x32_bf16(af, bfr, acc[f], 0, 0, 0);
            }
        }
    };

    loadRegs(0);
    writeLds(0);
    __syncthreads();
    int buf = 0;
#pragma unroll
    for (int kk = 0; kk < NSTEP; ++kk) {
        if (kk < NSTEP - 1) loadRegs(kk + 1);   // prefetch (HBM/L2 latency hides under MFMA)
        compute(buf);
        if (kk < NSTEP - 1) writeLds(buf ^ 1);
        __syncthreads();
        buf ^= 1;
    }

    // Epilogue: C/D layout col=lane&15, row=(lane>>4)*4+r  [m89]
    const int col_l = lane & 15;
    const int rgrp  = lane >> 4;
#pragma unroll
    for (int f = 0; f < 2; ++f) {
        const int col = n0 + wc * 32 + f * 16 + col_l;
        const float bv = bias[col];
#pragma unroll
        for (int r = 0; r < 4; ++r) {
            const int row = m0 + wr * 16 + rgrp * 4 + r;
            out[(size_t)row * OUT_F + col] = acc[f][r] + bv;
        }
    }
}

extern "C" void kernel_launch(void* const* d_in, const int* in_sizes, int n_in,
                              void* d_out, int out_size, void* d_ws, size_t ws_size,
                              hipStream_t stream) {
    const float* x = (const float*)d_in[0];       // [8192][256]
    const float* w = (const float*)d_in[1];       // [256][257]
    float* out = (float*)d_out;                   // [8192][256]

    short* Wcat = (short*)d_ws;                               // 256*512*2 = 262144 B
    float* bias = (float*)((char*)d_ws + (size_t)OUT_F * KC * 2);  // 1 KB

    prep_kernel<<<dim3(OUT_F), dim3(64), 0, stream>>>(w, Wcat, bias);
    skan_gemm<<<dim3(8192 / BM, OUT_F / BN), dim3(256), 0, stream>>>(x, Wcat, bias, out);
}